// Round 19
// baseline (286.653 us; speedup 1.0000x reference)
//
#include <hip/hip_runtime.h>
#include <hip/hip_bf16.h>

#define N_NODES 100000
#define D 128
#define EPT 250000
#define NT 7
#define NSEG (NT * N_NODES)   // 700000
#define ZROW N_NODES          // index of the all-zero row appended to xb
#define CAP 16                // bucket capacity per (type,node) segment

#define SCT_BLOCKS 977        // ceil(250000/256)
#define MRG_THREADS (SCT_BLOCKS * NT * 256)  // 1,750,784

typedef __attribute__((ext_vector_type(8))) short bf16x8;
typedef __attribute__((ext_vector_type(4))) float f32x4;

__device__ inline float b2f(unsigned int u16) {
    union { unsigned int i; float f; } v; v.i = u16 << 16; return v.f;
}
__device__ inline unsigned short f2b(float f) {
    union { float f; unsigned int i; } v; v.f = f;
    unsigned int r = v.i + 0x7fffu + ((v.i >> 16) & 1u);
    return (unsigned short)(r >> 16);
}
__device__ inline unsigned int pack2(float a, float b) {
    return (unsigned int)f2b(a) | ((unsigned int)f2b(b) << 16);
}

struct EPtrs { const int* e[NT]; };

// ---------------- prep_scatter: pipelined scatter + convert ----------------
// Grid (977, 7), uniform block work (R18 proven). NEW: the convert's float4
// loads are ISSUED before the atomic section, so the ~700cy atomic round-trip
// overlaps the convert-load latency instead of serializing ahead of it.

__global__ __launch_bounds__(256) void prep_scatter(EPtrs ep, int* __restrict__ cnt,
                                                    int* __restrict__ esrc,
                                                    const float4* __restrict__ x,
                                                    uint2* __restrict__ xb,
                                                    const float* __restrict__ W,
                                                    unsigned short* __restrict__ WbT) {
    int tid = threadIdx.x;
    int t = blockIdx.y;
    int i = blockIdx.x * 256 + tid;
    int gid = (t * SCT_BLOCKS + blockIdx.x) * 256 + tid;

    // issue edge loads
    bool ed = (i < EPT);
    int src = 0, dst = 0;
    if (ed) { src = ep.e[t][i]; dst = ep.e[t][EPT + i]; }

    // issue convert loads early (independent of the scatter)
    const int NX4 = N_NODES * D / 4;  // 3,200,000
    int k1 = gid + MRG_THREADS;
    bool b0 = gid < NX4, b1 = k1 < NX4;
    float4 xv0, xv1;
    if (b0) xv0 = x[gid];
    if (b1) xv1 = x[k1];

    // scatter: atomic + dependent store (latency hides under convert work)
    if (ed) {
        int seg = t * N_NODES + dst;
        int slot = atomicAdd(&cnt[seg], 1);
        if (slot < CAP) esrc[(size_t)seg * CAP + slot] = src;
    }

    // pack + store converts
    if (b0) xb[gid] = make_uint2(pack2(xv0.x, xv0.y), pack2(xv0.z, xv0.w));
    if (b1) xb[k1] = make_uint2(pack2(xv1.x, xv1.y), pack2(xv1.z, xv1.w));
    if (gid < 1024 * 128) {  // 131072
        int c = gid >> 10, tk = gid & 1023;
        WbT[gid] = f2b(W[tk * 128 + c] * 0.125f);  // fold /8 (exact pow2)
    }
    if (gid < 16) ((uint4*)xb)[(size_t)ZROW * 16 + gid] = make_uint4(0u, 0u, 0u, 0u);
}

// ---------------- fused aggregate + GEMM (K-split, bucket CSR, QUAD burst) ----------------
// R15's proven structure/numerics. NEW: phase 1a issues ALL 16 row-gather
// loads (types 0-3) as straight-line named-variable code before any
// accumulate; phase 1b a 12-load burst. All statically named -> cannot
// scratch-spill; worst case the scheduler serializes to PAIR-equivalent.
// Accumulation order per segment is unchanged -> bitwise-identical output.
//   1a: burst-gather types 0-3 -> LDS slots 0-3 | barrier
//   2a: GEMM k=0..511 -> acc                    | barrier
//   1b: burst-gather types 4-6 + global -> 0-3  | barrier
//   2b: GEMM k=512..1023 -> out

__device__ __forceinline__ uint4 ldrow(const unsigned short* __restrict__ xb, int idx, int chunk) {
    return *(const uint4*)(xb + (size_t)idx * 128 + chunk * 8);
}

__device__ __forceinline__ void accrow(float (&s)[8], uint4 v) {
    s[0] += b2f(v.x & 0xffffu);  s[1] += b2f(v.x >> 16);
    s[2] += b2f(v.y & 0xffffu);  s[3] += b2f(v.y >> 16);
    s[4] += b2f(v.z & 0xffffu);  s[5] += b2f(v.z >> 16);
    s[6] += b2f(v.w & 0xffffu);  s[7] += b2f(v.w >> 16);
}

__device__ __forceinline__ void tail4(const unsigned short* __restrict__ xb,
                                      const int* __restrict__ esrc, int start, int c,
                                      int chunk, float (&s)[8]) {
    if (c > 4) {
        int4 h = *(const int4*)(esrc + start + 4);
        int i5 = (c > 5) ? h.y : ZROW;
        int i6 = (c > 6) ? h.z : ZROW;
        int i7 = (c > 7) ? h.w : ZROW;
        uint4 v4 = ldrow(xb, h.x, chunk);
        uint4 v5 = ldrow(xb, i5, chunk);
        uint4 v6 = ldrow(xb, i6, chunk);
        uint4 v7 = ldrow(xb, i7, chunk);
        accrow(s, v4); accrow(s, v5); accrow(s, v6); accrow(s, v7);
        for (int j = 8; j < c; ++j) {  // P ~ 0.2%, j < CAP guaranteed
            uint4 v = ldrow(xb, esrc[start + j], chunk);
            accrow(s, v);
        }
    }
}

__global__ __launch_bounds__(512, 4) void fused_agg_gemm(const unsigned short* __restrict__ xb,
                                                         const int* __restrict__ cnt,
                                                         const int* __restrict__ esrc,
                                                         const unsigned short* __restrict__ WbT,
                                                         float* __restrict__ out) {
    __shared__ char lds[32 * 1024];  // 32 KB: [32 rows][512 bf16] (one K-half), swizzled

    int tid = threadIdx.x;
    int lane = tid & 63;
    int nloc = tid >> 4;       // 0..31
    int chunk = tid & 15;      // 0..15
    int tile0 = blockIdx.x * 32;
    int n = tile0 + nloc;

    char* rowp = lds + nloc * 1024;
    int rsw = (nloc & 7) << 4;
    float g[8] = {0.f, 0.f, 0.f, 0.f, 0.f, 0.f, 0.f, 0.f};
    int ctot = 0;
    float sa[8], sb[8], sc[8], sd[8];

#define LOADSEG(T, STV, CTV)                                                  \
    int STV, CTV;                                                             \
    {                                                                         \
        int seg_ = (T) * N_NODES + n;                                         \
        CTV = cnt[seg_];                                                      \
        CTV = (CTV > CAP) ? CAP : CTV;                                        \
        STV = seg_ * CAP;                                                     \
    }

#define EMIT(CTV, SLOT, S)                                                    \
    {                                                                         \
        int c_ = CTV;                                                         \
        ctot += c_;                                                           \
        float inv_ = 1.0f / (float)(c_ > 0 ? c_ : 1);                         \
        uint4 pk_;                                                            \
        pk_.x = pack2(S[0] * inv_, S[1] * inv_);                              \
        pk_.y = pack2(S[2] * inv_, S[3] * inv_);                              \
        pk_.z = pack2(S[4] * inv_, S[5] * inv_);                              \
        pk_.w = pack2(S[6] * inv_, S[7] * inv_);                              \
        *(uint4*)(rowp + (((SLOT) * 256 + chunk * 16) ^ rsw)) = pk_;          \
        for (int i_ = 0; i_ < 8; ++i_) g[i_] += S[i_];                        \
    }

// clamp + issue 4 row-gathers for one segment (no accumulation)
#define LD4(H, CTV, U0, U1, U2, U3)                                           \
    {                                                                         \
        int i0_ = (CTV > 0) ? H.x : ZROW;                                     \
        int i1_ = (CTV > 1) ? H.y : ZROW;                                     \
        int i2_ = (CTV > 2) ? H.z : ZROW;                                     \
        int i3_ = (CTV > 3) ? H.w : ZROW;                                     \
        U0 = ldrow(xb, i0_, chunk);                                           \
        U1 = ldrow(xb, i1_, chunk);                                           \
        U2 = ldrow(xb, i2_, chunk);                                           \
        U3 = ldrow(xb, i3_, chunk);                                           \
    }

#define ACC4(S, U0, U1, U2, U3)                                               \
    { accrow(S, U0); accrow(S, U1); accrow(S, U2); accrow(S, U3); }

    // ---- all 7 descriptors in parallel ----
    LOADSEG(0, st0, ct0)
    LOADSEG(1, st1, ct1)
    LOADSEG(2, st2, ct2)
    LOADSEG(3, st3, ct3)
    LOADSEG(4, st4, ct4)
    LOADSEG(5, st5, ct5)
    LOADSEG(6, st6, ct6)
    // ---- all 7 heads in parallel ----
    int4 h0 = *(const int4*)(esrc + st0);
    int4 h1 = *(const int4*)(esrc + st1);
    int4 h2 = *(const int4*)(esrc + st2);
    int4 h3 = *(const int4*)(esrc + st3);
    int4 h4 = *(const int4*)(esrc + st4);
    int4 h5 = *(const int4*)(esrc + st5);
    int4 h6 = *(const int4*)(esrc + st6);

    // ---- phase 1a: QUAD burst, types 0-3 -> LDS slots 0-3 ----
    {
        for (int i_ = 0; i_ < 8; ++i_) { sa[i_] = 0.f; sb[i_] = 0.f; sc[i_] = 0.f; sd[i_] = 0.f; }
        uint4 ua0, ua1, ua2, ua3, ub0, ub1, ub2, ub3;
        uint4 uc0, uc1, uc2, uc3, ud0, ud1, ud2, ud3;
        LD4(h0, ct0, ua0, ua1, ua2, ua3)
        LD4(h1, ct1, ub0, ub1, ub2, ub3)
        LD4(h2, ct2, uc0, uc1, uc2, uc3)
        LD4(h3, ct3, ud0, ud1, ud2, ud3)
        ACC4(sa, ua0, ua1, ua2, ua3)
        ACC4(sb, ub0, ub1, ub2, ub3)
        ACC4(sc, uc0, uc1, uc2, uc3)
        ACC4(sd, ud0, ud1, ud2, ud3)
        tail4(xb, esrc, st0, ct0, chunk, sa);
        tail4(xb, esrc, st1, ct1, chunk, sb);
        tail4(xb, esrc, st2, ct2, chunk, sc);
        tail4(xb, esrc, st3, ct3, chunk, sd);
        EMIT(ct0, 0, sa) EMIT(ct1, 1, sb) EMIT(ct2, 2, sc) EMIT(ct3, 3, sd)
    }

    __syncthreads();

    // ---- phase 2a: GEMM k = 0..511 ----
    int wvu = __builtin_amdgcn_readfirstlane(tid >> 6);
    int lr = lane & 15, lk = lane >> 4;
    f32x4 acc0 = (f32x4){0.f, 0.f, 0.f, 0.f};
    f32x4 acc1 = (f32x4){0.f, 0.f, 0.f, 0.f};
    const unsigned short* wb = WbT + (size_t)(wvu * 16 + lr) * 1024;
    int rx = (lr & 7) << 4;  // rows r and r+16 share (r&7) -> same XOR

#pragma unroll 4
    for (int k0 = 0; k0 < 512; k0 += 32) {
        int koff = (k0 + lk * 8) * 2;
        bf16x8 fa0 = *(const bf16x8*)(lds + ((lr * 1024 + koff) ^ rx));
        bf16x8 fa1 = *(const bf16x8*)(lds + (((lr + 16) * 1024 + koff) ^ rx));
        bf16x8 fb = *(const bf16x8*)(wb + k0 + lk * 8);
        acc0 = __builtin_amdgcn_mfma_f32_16x16x32_bf16(fa0, fb, acc0, 0, 0, 0);
        acc1 = __builtin_amdgcn_mfma_f32_16x16x32_bf16(fa1, fb, acc1, 0, 0, 0);
    }

    __syncthreads();

    // ---- phase 1b: TRIPLE burst, types 4-6 -> slots 0-2, global -> slot 3 ----
    {
        for (int i_ = 0; i_ < 8; ++i_) { sa[i_] = 0.f; sb[i_] = 0.f; sc[i_] = 0.f; }
        uint4 ua0, ua1, ua2, ua3, ub0, ub1, ub2, ub3, uc0, uc1, uc2, uc3;
        LD4(h4, ct4, ua0, ua1, ua2, ua3)
        LD4(h5, ct5, ub0, ub1, ub2, ub3)
        LD4(h6, ct6, uc0, uc1, uc2, uc3)
        ACC4(sa, ua0, ua1, ua2, ua3)
        ACC4(sb, ub0, ub1, ub2, ub3)
        ACC4(sc, uc0, uc1, uc2, uc3)
        tail4(xb, esrc, st4, ct4, chunk, sa);
        tail4(xb, esrc, st5, ct5, chunk, sb);
        tail4(xb, esrc, st6, ct6, chunk, sc);
        EMIT(ct4, 0, sa) EMIT(ct5, 1, sb) EMIT(ct6, 2, sc)
    }
    {
        float gi = 1.0f / (float)(ctot > 0 ? ctot : 1);
        uint4 pg;
        pg.x = pack2(g[0] * gi, g[1] * gi);
        pg.y = pack2(g[2] * gi, g[3] * gi);
        pg.z = pack2(g[4] * gi, g[5] * gi);
        pg.w = pack2(g[6] * gi, g[7] * gi);
        *(uint4*)(rowp + ((3 * 256 + chunk * 16) ^ rsw)) = pg;
    }

    __syncthreads();

    // ---- phase 2b: GEMM k = 512..1023, then store ----
#pragma unroll 4
    for (int k0 = 0; k0 < 512; k0 += 32) {
        int koff = (k0 + lk * 8) * 2;
        bf16x8 fa0 = *(const bf16x8*)(lds + ((lr * 1024 + koff) ^ rx));
        bf16x8 fa1 = *(const bf16x8*)(lds + (((lr + 16) * 1024 + koff) ^ rx));
        bf16x8 fb = *(const bf16x8*)(wb + 512 + k0 + lk * 8);
        acc0 = __builtin_amdgcn_mfma_f32_16x16x32_bf16(fa0, fb, acc0, 0, 0, 0);
        acc1 = __builtin_amdgcn_mfma_f32_16x16x32_bf16(fa1, fb, acc1, 0, 0, 0);
    }

    int col = wvu * 16 + lr;
    int n0 = tile0 + lk * 4;
#pragma unroll
    for (int qq = 0; qq < 4; ++qq) {
        out[(size_t)(n0 + qq) * 128 + col] = acc0[qq];
        out[(size_t)(n0 + 16 + qq) * 128 + col] = acc1[qq];
    }
}

// ---------------- launch: memset + 2 dispatches ----------------
// ws layout:
//   cnt  @ 0          : 2,800,000
//   WbT  @ 2,800,000  : 262,144
//   xb   @ 3,062,144  : 25,600,256 (incl. zero row)
//   esrc @ 28,662,400 : 44,800,000 (700K segments x CAP=16 ints)
//   total ~73.5 MB

extern "C" void kernel_launch(void* const* d_in, const int* in_sizes, int n_in,
                              void* d_out, int out_size, void* d_ws, size_t ws_size,
                              hipStream_t stream) {
    const float* x = (const float*)d_in[0];
    const float* W = (const float*)d_in[1];
    EPtrs ep;
    for (int t = 0; t < NT; ++t) ep.e[t] = (const int*)d_in[2 + t];
    float* out = (float*)d_out;

    char* ws = (char*)d_ws;
    int* cnt            = (int*)(ws + 0);
    unsigned short* WbT = (unsigned short*)(ws + 2800000);
    unsigned short* xb  = (unsigned short*)(ws + 3062144);
    int* esrc           = (int*)(ws + 28662400);

    hipMemsetAsync(cnt, 0, NSEG * sizeof(int), stream);

    dim3 mgrid(SCT_BLOCKS, NT);
    prep_scatter<<<mgrid, 256, 0, stream>>>(ep, cnt, esrc, (const float4*)x, (uint2*)xb, W, WbT);

    int nblocks = N_NODES / 32;  // 3125, exact
    fused_agg_gemm<<<nblocks, 512, 0, stream>>>(xb, cnt, esrc, WbT, out);
}

// Round 20
// 272.630 us; speedup vs baseline: 1.0514x; 1.0514x over previous
//
#include <hip/hip_runtime.h>
#include <hip/hip_bf16.h>

#define N_NODES 100000
#define D 128
#define EPT 250000
#define NT 7
#define NSEG (NT * N_NODES)   // 700000
#define ZROW N_NODES          // index of the all-zero row appended to xb
#define CAP 16                // bucket capacity per (type,node) segment

#define SCT_BLOCKS 977        // ceil(250000/256)
#define MRG_THREADS (SCT_BLOCKS * NT * 256)  // 1,750,784

typedef __attribute__((ext_vector_type(8))) short bf16x8;
typedef __attribute__((ext_vector_type(4))) float f32x4;

__device__ inline float b2f(unsigned int u16) {
    union { unsigned int i; float f; } v; v.i = u16 << 16; return v.f;
}
__device__ inline unsigned short f2b(float f) {
    union { float f; unsigned int i; } v; v.f = f;
    unsigned int r = v.i + 0x7fffu + ((v.i >> 16) & 1u);
    return (unsigned short)(r >> 16);
}
__device__ inline unsigned int pack2(float a, float b) {
    return (unsigned int)f2b(a) | ((unsigned int)f2b(b) << 16);
}

struct EPtrs { const int* e[NT]; };

// ---------------- prep_scatter: UNIFORM per-block scatter + convert (R18 proven) ----------------
// Grid (977, 7). Every block: (a) scatter its 256-edge chunk of type
// blockIdx.y (atomics issue immediately, latency-bound), then (b) grid-stride
// convert x->bf16 / build WbT (BW-bound streaming fills the atomic-latency
// shadow). Homogeneous block work -> single occupancy shift, true overlap.

__global__ __launch_bounds__(256) void prep_scatter(EPtrs ep, int* __restrict__ cnt,
                                                    int* __restrict__ esrc,
                                                    const float4* __restrict__ x,
                                                    uint2* __restrict__ xb,
                                                    const float* __restrict__ W,
                                                    unsigned short* __restrict__ WbT) {
    int tid = threadIdx.x;
    int t = blockIdx.y;
    int i = blockIdx.x * 256 + tid;

    // (a) scatter chunk
    if (i < EPT) {
        int src = ep.e[t][i];
        int dst = ep.e[t][EPT + i];
        int seg = t * N_NODES + dst;
        int slot = atomicAdd(&cnt[seg], 1);
        if (slot < CAP) esrc[(size_t)seg * CAP + slot] = src;
    }

    // (b) convert slice (grid-stride over all blocks)
    int gid = (t * SCT_BLOCKS + blockIdx.x) * 256 + tid;
    for (int k = gid; k < N_NODES * D / 4; k += MRG_THREADS) {  // 3.2M float4, ~2 iters
        float4 v = x[k];
        xb[k] = make_uint2(pack2(v.x, v.y), pack2(v.z, v.w));
    }
    if (gid < 1024 * 128) {  // 131072
        int c = gid >> 10, tk = gid & 1023;
        WbT[gid] = f2b(W[tk * 128 + c] * 0.125f);  // fold /8 (exact pow2)
    }
    if (gid < 16) ((uint4*)xb)[(size_t)ZROW * 16 + gid] = make_uint4(0u, 0u, 0u, 0u);
}

// ---------------- fused aggregate + GEMM (K-split, bucket CSR) ----------------
// EXACT R15 kernel (proven 178 us, VGPR 64, no spill; QUAD burst (R19) and
// predication (R17) both regressed — 8 in-flight PAIR gathers at VGPR=64 is
// the source-level optimum).
//   1a: gather types 0-3 -> LDS slots 0-3      | barrier
//   2a: GEMM k=0..511 -> acc                   | barrier
//   1b: gather types 4-6 + global -> slots 0-3 | barrier
//   2b: GEMM k=512..1023 -> out

__device__ __forceinline__ uint4 ldrow(const unsigned short* __restrict__ xb, int idx, int chunk) {
    return *(const uint4*)(xb + (size_t)idx * 128 + chunk * 8);
}

__device__ __forceinline__ void accrow(float (&s)[8], uint4 v) {
    s[0] += b2f(v.x & 0xffffu);  s[1] += b2f(v.x >> 16);
    s[2] += b2f(v.y & 0xffffu);  s[3] += b2f(v.y >> 16);
    s[4] += b2f(v.z & 0xffffu);  s[5] += b2f(v.z >> 16);
    s[6] += b2f(v.w & 0xffffu);  s[7] += b2f(v.w >> 16);
}

__device__ __forceinline__ void main4(const unsigned short* __restrict__ xb, int4 h, int c,
                                      int chunk, float (&s)[8]) {
    int i0 = (c > 0) ? h.x : ZROW;
    int i1 = (c > 1) ? h.y : ZROW;
    int i2 = (c > 2) ? h.z : ZROW;
    int i3 = (c > 3) ? h.w : ZROW;
    uint4 v0 = ldrow(xb, i0, chunk);
    uint4 v1 = ldrow(xb, i1, chunk);
    uint4 v2 = ldrow(xb, i2, chunk);
    uint4 v3 = ldrow(xb, i3, chunk);
    accrow(s, v0); accrow(s, v1); accrow(s, v2); accrow(s, v3);
}

__device__ __forceinline__ void tail4(const unsigned short* __restrict__ xb,
                                      const int* __restrict__ esrc, int start, int c,
                                      int chunk, float (&s)[8]) {
    if (c > 4) {
        int4 h = *(const int4*)(esrc + start + 4);
        int i5 = (c > 5) ? h.y : ZROW;
        int i6 = (c > 6) ? h.z : ZROW;
        int i7 = (c > 7) ? h.w : ZROW;
        uint4 v4 = ldrow(xb, h.x, chunk);
        uint4 v5 = ldrow(xb, i5, chunk);
        uint4 v6 = ldrow(xb, i6, chunk);
        uint4 v7 = ldrow(xb, i7, chunk);
        accrow(s, v4); accrow(s, v5); accrow(s, v6); accrow(s, v7);
        for (int j = 8; j < c; ++j) {  // P ~ 0.2%, j < CAP guaranteed
            uint4 v = ldrow(xb, esrc[start + j], chunk);
            accrow(s, v);
        }
    }
}

__global__ __launch_bounds__(512, 4) void fused_agg_gemm(const unsigned short* __restrict__ xb,
                                                         const int* __restrict__ cnt,
                                                         const int* __restrict__ esrc,
                                                         const unsigned short* __restrict__ WbT,
                                                         float* __restrict__ out) {
    __shared__ char lds[32 * 1024];  // 32 KB: [32 rows][512 bf16] (one K-half), swizzled

    int tid = threadIdx.x;
    int lane = tid & 63;
    int nloc = tid >> 4;       // 0..31
    int chunk = tid & 15;      // 0..15
    int tile0 = blockIdx.x * 32;
    int n = tile0 + nloc;

    char* rowp = lds + nloc * 1024;
    int rsw = (nloc & 7) << 4;
    float g[8] = {0.f, 0.f, 0.f, 0.f, 0.f, 0.f, 0.f, 0.f};
    int ctot = 0;
    float sa[8], sb[8];

#define LOADSEG(T, STV, CTV)                                                  \
    int STV, CTV;                                                             \
    {                                                                         \
        int seg_ = (T) * N_NODES + n;                                         \
        CTV = cnt[seg_];                                                      \
        CTV = (CTV > CAP) ? CAP : CTV;                                        \
        STV = seg_ * CAP;                                                     \
    }

#define EMIT(CTV, SLOT, S)                                                    \
    {                                                                         \
        int c_ = CTV;                                                         \
        ctot += c_;                                                           \
        float inv_ = 1.0f / (float)(c_ > 0 ? c_ : 1);                         \
        uint4 pk_;                                                            \
        pk_.x = pack2(S[0] * inv_, S[1] * inv_);                              \
        pk_.y = pack2(S[2] * inv_, S[3] * inv_);                              \
        pk_.z = pack2(S[4] * inv_, S[5] * inv_);                              \
        pk_.w = pack2(S[6] * inv_, S[7] * inv_);                              \
        *(uint4*)(rowp + (((SLOT) * 256 + chunk * 16) ^ rsw)) = pk_;          \
        for (int i_ = 0; i_ < 8; ++i_) g[i_] += S[i_];                        \
    }

#define PAIRH(HA, STA, CTA, HB, STB, CTB, SLA, SLB)                           \
    {                                                                         \
        for (int i_ = 0; i_ < 8; ++i_) { sa[i_] = 0.f; sb[i_] = 0.f; }        \
        main4(xb, HA, CTA, chunk, sa);                                        \
        main4(xb, HB, CTB, chunk, sb);                                        \
        tail4(xb, esrc, STA, CTA, chunk, sa);                                 \
        tail4(xb, esrc, STB, CTB, chunk, sb);                                 \
        EMIT(CTA, SLA, sa); EMIT(CTB, SLB, sb);                               \
    }

    // ---- all 7 descriptors in parallel (one cnt load each; start is computed) ----
    LOADSEG(0, st0, ct0)
    LOADSEG(1, st1, ct1)
    LOADSEG(2, st2, ct2)
    LOADSEG(3, st3, ct3)
    LOADSEG(4, st4, ct4)
    LOADSEG(5, st5, ct5)
    LOADSEG(6, st6, ct6)
    // ---- all 7 heads in parallel (bucket base is address-independent of cnt) ----
    int4 h0 = *(const int4*)(esrc + st0);
    int4 h1 = *(const int4*)(esrc + st1);
    int4 h2 = *(const int4*)(esrc + st2);
    int4 h3 = *(const int4*)(esrc + st3);
    int4 h4 = *(const int4*)(esrc + st4);
    int4 h5 = *(const int4*)(esrc + st5);
    int4 h6 = *(const int4*)(esrc + st6);

    // ---- phase 1a: types 0-3 -> LDS slots 0-3 ----
    PAIRH(h0, st0, ct0, h1, st1, ct1, 0, 1)
    PAIRH(h2, st2, ct2, h3, st3, ct3, 2, 3)

    __syncthreads();

    // ---- phase 2a: GEMM k = 0..511 ----
    int wvu = __builtin_amdgcn_readfirstlane(tid >> 6);
    int lr = lane & 15, lk = lane >> 4;
    f32x4 acc0 = (f32x4){0.f, 0.f, 0.f, 0.f};
    f32x4 acc1 = (f32x4){0.f, 0.f, 0.f, 0.f};
    const unsigned short* wb = WbT + (size_t)(wvu * 16 + lr) * 1024;
    int rx = (lr & 7) << 4;  // rows r and r+16 share (r&7) -> same XOR

#pragma unroll 4
    for (int k0 = 0; k0 < 512; k0 += 32) {
        int koff = (k0 + lk * 8) * 2;
        bf16x8 fa0 = *(const bf16x8*)(lds + ((lr * 1024 + koff) ^ rx));
        bf16x8 fa1 = *(const bf16x8*)(lds + (((lr + 16) * 1024 + koff) ^ rx));
        bf16x8 fb = *(const bf16x8*)(wb + k0 + lk * 8);
        acc0 = __builtin_amdgcn_mfma_f32_16x16x32_bf16(fa0, fb, acc0, 0, 0, 0);
        acc1 = __builtin_amdgcn_mfma_f32_16x16x32_bf16(fa1, fb, acc1, 0, 0, 0);
    }

    __syncthreads();

    // ---- phase 1b: types 4-6 + global -> LDS slots 0-3 ----
    PAIRH(h4, st4, ct4, h5, st5, ct5, 0, 1)
    {
        for (int i_ = 0; i_ < 8; ++i_) sa[i_] = 0.f;
        main4(xb, h6, ct6, chunk, sa);
        tail4(xb, esrc, st6, ct6, chunk, sa);
        EMIT(ct6, 2, sa)
    }
    {
        float gi = 1.0f / (float)(ctot > 0 ? ctot : 1);
        uint4 pg;
        pg.x = pack2(g[0] * gi, g[1] * gi);
        pg.y = pack2(g[2] * gi, g[3] * gi);
        pg.z = pack2(g[4] * gi, g[5] * gi);
        pg.w = pack2(g[6] * gi, g[7] * gi);
        *(uint4*)(rowp + ((3 * 256 + chunk * 16) ^ rsw)) = pg;
    }

    __syncthreads();

    // ---- phase 2b: GEMM k = 512..1023, then store ----
#pragma unroll 4
    for (int k0 = 0; k0 < 512; k0 += 32) {
        int koff = (k0 + lk * 8) * 2;
        bf16x8 fa0 = *(const bf16x8*)(lds + ((lr * 1024 + koff) ^ rx));
        bf16x8 fa1 = *(const bf16x8*)(lds + (((lr + 16) * 1024 + koff) ^ rx));
        bf16x8 fb = *(const bf16x8*)(wb + 512 + k0 + lk * 8);
        acc0 = __builtin_amdgcn_mfma_f32_16x16x32_bf16(fa0, fb, acc0, 0, 0, 0);
        acc1 = __builtin_amdgcn_mfma_f32_16x16x32_bf16(fa1, fb, acc1, 0, 0, 0);
    }

    int col = wvu * 16 + lr;
    int n0 = tile0 + lk * 4;
#pragma unroll
    for (int qq = 0; qq < 4; ++qq) {
        out[(size_t)(n0 + qq) * 128 + col] = acc0[qq];
        out[(size_t)(n0 + 16 + qq) * 128 + col] = acc1[qq];
    }
}

// ---------------- launch: memset + 2 dispatches (R18 proven) ----------------
// ws layout:
//   cnt  @ 0          : 2,800,000
//   WbT  @ 2,800,000  : 262,144
//   xb   @ 3,062,144  : 25,600,256 (incl. zero row)
//   esrc @ 28,662,400 : 44,800,000 (700K segments x CAP=16 ints)
//   total ~73.5 MB

extern "C" void kernel_launch(void* const* d_in, const int* in_sizes, int n_in,
                              void* d_out, int out_size, void* d_ws, size_t ws_size,
                              hipStream_t stream) {
    const float* x = (const float*)d_in[0];
    const float* W = (const float*)d_in[1];
    EPtrs ep;
    for (int t = 0; t < NT; ++t) ep.e[t] = (const int*)d_in[2 + t];
    float* out = (float*)d_out;

    char* ws = (char*)d_ws;
    int* cnt            = (int*)(ws + 0);
    unsigned short* WbT = (unsigned short*)(ws + 2800000);
    unsigned short* xb  = (unsigned short*)(ws + 3062144);
    int* esrc           = (int*)(ws + 28662400);

    hipMemsetAsync(cnt, 0, NSEG * sizeof(int), stream);

    dim3 mgrid(SCT_BLOCKS, NT);
    prep_scatter<<<mgrid, 256, 0, stream>>>(ep, cnt, esrc, (const float4*)x, (uint2*)xb, W, WbT);

    int nblocks = N_NODES / 32;  // 3125, exact
    fused_agg_gemm<<<nblocks, 512, 0, stream>>>(xb, cnt, esrc, WbT, out);
}